// Round 11
// baseline (1479.464 us; speedup 1.0000x reference)
//
#include <hip/hip_runtime.h>
#include <math.h>

#define NN 2048
#define DIMF 256
#define HIDN 128
#define NG 8
#define NEDGES 32768
#define W32 32
#define TRI_CAP 131072
#define TRI_LDS 4864

typedef unsigned long long u64;
typedef unsigned char u8;
typedef unsigned short u16;

// ---------------- build adjacency ----------------
__global__ void k_init(u64* __restrict__ rowbits, int* __restrict__ segstart) {
  int i = blockIdx.x * blockDim.x + threadIdx.x;
  for (int k = i; k < NN * W32; k += gridDim.x * blockDim.x) rowbits[k] = 0ull;
  if (i <= NG) segstart[i] = NN;
}

__global__ void k_edges(const int* __restrict__ ei, u64* __restrict__ rowbits) {
  int e = blockIdx.x * blockDim.x + threadIdx.x;
  if (e >= NEDGES) return;
  int u = ei[e], v = ei[NEDGES + e];
  atomicOr(&rowbits[((size_t)u << 5) + (v >> 6)], 1ull << (v & 63));
}

// deg (inline popcount) + exclusive scan -> rowptr, + segment bounds (fused)
__global__ void k_degscan(const u64* __restrict__ rowbits, const int* __restrict__ batch,
                          int* __restrict__ segstart, int* __restrict__ out) {
  __shared__ int part[256];
  int t = threadIdx.x;
  int v[8]; int s = 0;
  for (int k = 0; k < 8; ++k) {
    int node = t * 8 + k;
    int c = 0;
    for (int w = 0; w < W32; ++w) c += __popcll(rowbits[((size_t)node << 5) + w]);
    v[k] = c; s += c;
    if (node == 0 || batch[node] != batch[node - 1]) segstart[batch[node]] = node;
  }
  part[t] = s;
  __syncthreads();
  for (int off = 1; off < 256; off <<= 1) {
    int y = (t >= off) ? part[t - off] : 0;
    __syncthreads();
    part[t] += y;
    __syncthreads();
  }
  int run = part[t] - s;
  for (int k = 0; k < 8; ++k) { out[t * 8 + k] = run; run += v[k]; }
  if (t == 255) out[NN] = part[255];
}

// exclusive scan of 2048 ints -> out[0..2048]
__global__ void k_scan2048(const int* __restrict__ in, int* __restrict__ out) {
  __shared__ int part[256];
  int t = threadIdx.x;
  int v[8]; int s = 0;
  for (int k = 0; k < 8; ++k) { v[k] = in[t * 8 + k]; s += v[k]; }
  part[t] = s;
  __syncthreads();
  for (int off = 1; off < 256; off <<= 1) {
    int y = (t >= off) ? part[t - off] : 0;
    __syncthreads();
    part[t] += y;
    __syncthreads();
  }
  int run = part[t] - s;
  for (int k = 0; k < 8; ++k) { out[t * 8 + k] = run; run += v[k]; }
  if (t == 255) out[NN] = part[255];
}

// extract CSR + count triangle pairs (fused)
__global__ void k_extract(const u64* __restrict__ rowbits, const int* __restrict__ rp,
                          int* __restrict__ col, int* __restrict__ cnt) {
  int i = blockIdx.x * blockDim.x + threadIdx.x;
  if (i >= NN) return;
  const u64* ri = rowbits + ((size_t)i << 5);
  int o = rp[i];
  for (int w = 0; w < W32; ++w) {
    u64 b = ri[w];
    while (b) { col[o++] = (w << 6) + __builtin_ctzll(b); b &= b - 1; }
  }
  int c = 0;
  for (int e = rp[i]; e < o; ++e) {
    const u64* ra = rowbits + ((size_t)col[e] << 5);
    for (int w = 0; w < W32; ++w) c += __popcll(ra[w] & ri[w]);
  }
  cnt[i] = c;
}

__global__ void k_trifill(const u64* __restrict__ rowbits, const int* __restrict__ rp,
                          const int* __restrict__ col, const int* __restrict__ tp,
                          int2* __restrict__ tri) {
  int i = blockIdx.x * blockDim.x + threadIdx.x;
  if (i >= NN) return;
  const u64* ri = rowbits + ((size_t)i << 5);
  int o = tp[i];
  for (int e = rp[i]; e < rp[i + 1]; ++e) {
    int a = col[e];
    const u64* ra = rowbits + ((size_t)a << 5);
    for (int w = 0; w < W32; ++w) {
      u64 b = ra[w] & ri[w];
      while (b) {
        int j = (w << 6) + __builtin_ctzll(b);
        if (o < TRI_CAP) tri[o] = make_int2(a, j);
        ++o;
        b &= b - 1;
      }
    }
  }
}

// ---------------- entropy term ----------------
__global__ void k_V(const float* __restrict__ x, const int* __restrict__ rp,
                    const int* __restrict__ col, float* __restrict__ V) {
  int i = blockIdx.x; int t = threadIdx.x; // 256 threads = dims
  float xi = x[i * DIMF + t];
  float s1 = 0.f, s2 = 0.f;
  int r0 = rp[i], r1 = rp[i + 1];
  for (int e = r0; e < r1; ++e) {
    float xj = x[col[e] * DIMF + t];
    s1 += xj; s2 += xj * xj;
  }
  float dg = (float)(r1 - r0);
  float val = dg * xi * xi - 2.f * xi * s1 + s2;
  __shared__ double red[DIMF];
  red[t] = (double)val * (double)val;
  __syncthreads();
  for (int off = DIMF / 2; off > 0; off >>= 1) { if (t < off) red[t] += red[t + off]; __syncthreads(); }
  if (t == 0) V[i] = (float)sqrt(red[0]);
}

__global__ void k_soft(const float* __restrict__ V, const int* __restrict__ segstart,
                       float* __restrict__ ent, double* __restrict__ seggamma) {
  int g = blockIdx.x; int t = threadIdx.x;
  int s = segstart[g];
  int e = NN;
  for (int gg = g + 1; gg <= NG; ++gg) { int v = segstart[gg]; if (v < e) e = v; }
  if (s >= e) { if (t == 0) seggamma[g] = 0.0; return; }
  __shared__ float fm[256];
  __shared__ double dd[256];
  float m = -3.0e38f;
  for (int i = s + t; i < e; i += 256) m = fmaxf(m, V[i]);
  fm[t] = m; __syncthreads();
  for (int off = 128; off > 0; off >>= 1) { if (t < off) fm[t] = fmaxf(fm[t], fm[t + off]); __syncthreads(); }
  float mx = fm[0];
  __syncthreads();
  double sum = 0.0;
  for (int i = s + t; i < e; i += 256) sum += exp((double)V[i] - (double)mx);
  dd[t] = sum; __syncthreads();
  for (int off = 128; off > 0; off >>= 1) { if (t < off) dd[t] += dd[t + off]; __syncthreads(); }
  double tot = dd[0];
  __syncthreads();
  double gs = 0.0;
  for (int i = s + t; i < e; i += 256) {
    double P = exp((double)V[i] - (double)mx) / tot;
    float ev = (P > 0.0) ? (float)(-P * log(P)) : 0.f;
    ent[i] = ev;
    gs += (double)ev;
  }
  dd[t] = gs; __syncthreads();
  for (int off = 128; off > 0; off >>= 1) { if (t < off) dd[t] += dd[t + off]; __syncthreads(); }
  if (t == 0) seggamma[g] = dd[0];
}

// ---------------- GIN MLPs ----------------
__global__ void k_agg1(const float* __restrict__ ent, const int* __restrict__ rp,
                       const int* __restrict__ col, float* __restrict__ agg) {
  int i = blockIdx.x * blockDim.x + threadIdx.x;
  if (i >= NN) return;
  float a = ent[i];
  for (int e = rp[i]; e < rp[i + 1]; ++e) a += ent[col[e]];
  agg[i] = a;
}

// FROMAGG=1: value = relu(src[i]*w1[k]+b1[k]) computed on the fly
template<int FROMAGG>
__global__ void k_bn(const float* __restrict__ src, const float* __restrict__ w1,
                     const float* __restrict__ b1, const float* __restrict__ g,
                     const float* __restrict__ be, float* __restrict__ scale,
                     float* __restrict__ shift) {
  int k = blockIdx.x; int tid = threadIdx.x; // 256 threads per column
  __shared__ double red[256];
  float wk = 0.f, bk = 0.f;
  if (FROMAGG) { wk = w1[k]; bk = b1[k]; }
  double s = 0.0;
  for (int i = tid; i < NN; i += 256) {
    float v;
    if (FROMAGG) { v = src[i] * wk + bk; v = v > 0.f ? v : 0.f; }
    else v = src[i * HIDN + k];
    s += (double)v;
  }
  red[tid] = s; __syncthreads();
  for (int off = 128; off > 0; off >>= 1) { if (tid < off) red[tid] += red[tid + off]; __syncthreads(); }
  double mu = red[0] / NN;
  __syncthreads();
  double vv = 0.0;
  for (int i = tid; i < NN; i += 256) {
    float v;
    if (FROMAGG) { v = src[i] * wk + bk; v = v > 0.f ? v : 0.f; }
    else v = src[i * HIDN + k];
    double dv = (double)v - mu; vv += dv * dv;
  }
  red[tid] = vv; __syncthreads();
  for (int off = 128; off > 0; off >>= 1) { if (tid < off) red[tid] += red[tid + off]; __syncthreads(); }
  if (tid == 0) {
    float var = (float)(red[0] / NN);
    float sc = g[k] / sqrtf(var + 1e-5f);
    scale[k] = sc;
    shift[k] = be[k] - (float)mu * sc;
  }
}

// PRE: 0 = raw src, 1 = src*scale+shift, 2 = relu(agg[r]*lw+lb)*scale+shift
template<int PRE, int RELU>
__global__ void k_mm(const float* __restrict__ in, const float* __restrict__ Wm,
                     const float* __restrict__ bias, const float* __restrict__ scale,
                     const float* __restrict__ shift, const float* __restrict__ lw,
                     const float* __restrict__ lb, float* __restrict__ out) {
  __shared__ float ti[8][HIDN];
  int r0 = blockIdx.x * 8; int t = threadIdx.x; // 128 threads
  for (int r = 0; r < 8; ++r) {
    float v;
    if (PRE == 2) {
      v = in[r0 + r] * lw[t] + lb[t];
      v = v > 0.f ? v : 0.f;
      v = v * scale[t] + shift[t];
    } else {
      v = in[(r0 + r) * HIDN + t];
      if (PRE == 1) v = v * scale[t] + shift[t];
    }
    ti[r][t] = v;
  }
  __syncthreads();
  float acc[8];
  #pragma unroll
  for (int r = 0; r < 8; ++r) acc[r] = 0.f;
  for (int k = 0; k < HIDN; ++k) {
    float w = Wm[k * HIDN + t];
    #pragma unroll
    for (int r = 0; r < 8; ++r) acc[r] += ti[r][k] * w;
  }
  for (int r = 0; r < 8; ++r) {
    float v = acc[r] + bias[t];
    if (RELU) v = fmaxf(v, 0.f);
    out[(r0 + r) * HIDN + t] = v;
  }
}

__global__ void k_agg128(const float* __restrict__ h, const int* __restrict__ rp,
                         const int* __restrict__ col, float* __restrict__ agg) {
  int i = blockIdx.x; int t = threadIdx.x; // 128 threads
  float a = h[i * HIDN + t];
  for (int e = rp[i]; e < rp[i + 1]; ++e) a += h[col[e] * HIDN + t];
  agg[i * HIDN + t] = a;
}

__global__ void k_lin3(const float* __restrict__ tn, const float* __restrict__ scale,
                       const float* __restrict__ shift, const float* __restrict__ w32,
                       const float* __restrict__ b32, float* __restrict__ p) {
  int i = blockIdx.x; int t = threadIdx.x; // 128
  float v = (tn[i * HIDN + t] * scale[t] + shift[t]) * w32[t];
  __shared__ float red[HIDN];
  red[t] = v; __syncthreads();
  for (int off = 64; off > 0; off >>= 1) { if (t < off) red[t] += red[t + off]; __syncthreads(); }
  if (t == 0) {
    float h3 = red[0] + b32[0];
    p[i] = 1.f / (1.f + expf(-h3));
  }
}

// ---------------- sort (descending p, stable) ----------------
__global__ void __launch_bounds__(1024, 1) k_sort(const float* __restrict__ p,
                                                  int* __restrict__ order) {
  __shared__ u64 s[NN];
  int t = threadIdx.x; // 1024
  for (int k = t; k < NN; k += 1024) {
    unsigned b = __float_as_uint(p[k]);
    unsigned ss = (b & 0x80000000u) ? ~b : (b | 0x80000000u);
    s[k] = ((u64)(~ss) << 32) | (unsigned)k;
  }
  __syncthreads();
  for (int k = 2; k <= NN; k <<= 1) {
    for (int j = k >> 1; j > 0; j >>= 1) {
      for (int i = t; i < NN; i += 1024) {
        int ixj = i ^ j;
        if (ixj > i) {
          bool up = ((i & k) == 0);
          u64 a = s[i], b = s[ixj];
          if ((a > b) == up) { s[i] = b; s[ixj] = a; }
        }
      }
      __syncthreads();
    }
  }
  order[t] = (int)(s[t] & 0xFFFFFFFFull);
  order[t + 1024] = (int)(s[t + 1024] & 0xFFFFFFFFull);
}

// ---------------- greedy: compacted speculative batch (q0/e0/loss fused in) --------
#define DPP2(ctrl)                                                                        \
  a += __int_as_float(__builtin_amdgcn_update_dpp(0, __float_as_int(a), ctrl, 0xf, 0xf, true)); \
  b += __int_as_float(__builtin_amdgcn_update_dpp(0, __float_as_int(b), ctrl, 0xf, 0xf, true));

__device__ __forceinline__ void red2(float& a, float& b) {
  DPP2(0x111)
  DPP2(0x112)
  DPP2(0x114)
  DPP2(0x118)
  DPP2(0x142)
  DPP2(0x143)
  a = __int_as_float(__builtin_amdgcn_readlane(__float_as_int(a), 63));
  b = __int_as_float(__builtin_amdgcn_readlane(__float_as_int(b), 63));
}

__global__ void __launch_bounds__(1024, 1) k_greedy(
    const int* __restrict__ rp, const int* __restrict__ col,
    const int* __restrict__ tp, const int2* __restrict__ tri,
    const int* __restrict__ order, const float* __restrict__ p,
    const float* __restrict__ ent, const double* __restrict__ seggam,
    double* __restrict__ scal, u8* __restrict__ selb_g) {
  __shared__ float2 dq[NN];           // 16 KB {d, q}
  __shared__ float2 ee[NN];           // 16 KB {ent, E}
  __shared__ u16 colL[NEDGES];        // 64 KB
  __shared__ u16 ordl[NN];            // 4 KB
  __shared__ uint2 rtP[NN + 1];       // 16 KB {rp|tp<<16 at i, at i+1}
  __shared__ ushort2 triL[TRI_LDS];   // 19 KB
  __shared__ unsigned decidedL[64], selL[64];
  __shared__ unsigned maskL[2];
  __shared__ float4 svA[2][16];       // {S1, S2, d0, st}
  __shared__ float svQ[2][16];        // q[idx] saved at eval time
  __shared__ int   svP[2][16];        // order-position of slot w
  __shared__ u64 wbalL[16];           // window live-bits (1024 positions)
  __shared__ double rr[36];
  int t = threadIdx.x;
  int w = t >> 6, lane = t & 63;

  for (int i = t; i < NN; i += 1024) {
    dq[i].x = p[i];
    ee[i].x = ent[i];
    ordl[i] = (u16)order[i];
    int tv0 = tp[i]; if (tv0 > 65535) tv0 = 65535;
    int tv1 = tp[i + 1]; if (tv1 > 65535) tv1 = 65535;
    rtP[i] = make_uint2((unsigned)rp[i] | ((unsigned)tv0 << 16),
                        (unsigned)rp[i + 1] | ((unsigned)tv1 << 16));
  }
  for (int i = t; i < NEDGES; i += 1024) colL[i] = (u16)col[i];
  for (int i = t; i < TRI_LDS; i += 1024) {
    int2 ab = tri[i];
    triL[i] = make_ushort2((u16)(ab.x & 2047), (u16)(ab.y & 2047));
  }
  if (t < 64) { decidedL[t] = 0u; selL[t] = 0u; }
  if (t < 2) maskL[t] = 0u;
  __syncthreads();
  // q0/e0 from LDS (same CSR-serial order as the old k_q0) + isolated pre-decide
  for (int i = t; i < NN; i += 1024) {
    int r0 = rtP[i].x & 0xffff, r1 = rtP[i].y & 0xffff;
    float qs = 0.f, es = 0.f;
    for (int e = r0; e < r1; ++e) {
      int j = colL[e];
      float pj = dq[j].x;
      qs += pj; es += ee[j].x * pj;
    }
    dq[i].y = qs; ee[i].y = es;
    if (r0 == r1) {
      atomicOr(&decidedL[i >> 5], 1u << (i & 31));
      atomicOr(&selL[i >> 5], 1u << (i & 31));
    }
  }
  __syncthreads();
  // loss scalars (same reduction pattern as old k_sortloss)
  {
    double a = 0.0, b = 0.0;
    for (int i = t; i < NN; i += 1024) {
      a += (double)ee[i].x * (double)dq[i].x;
      b += (double)dq[i].x * (double)dq[i].y;
    }
    for (int off = 32; off; off >>= 1) { a += __shfl_down(a, off); b += __shfl_down(b, off); }
    if ((t & 63) == 0) { rr[(t >> 6) * 2] = a; rr[(t >> 6) * 2 + 1] = b; }
  }
  __syncthreads();
  if (t == 0) {
    double A = 0.0, Bb = 0.0, g = 0.0;
    for (int i = 0; i < 16; ++i) { A += rr[2 * i]; Bb += rr[2 * i + 1]; }
    for (int gg = 0; gg < NG; ++gg) g += seggam[gg];
    rr[32] = g; rr[33] = A; rr[34] = Bb; rr[35] = g - A + Bb;
    scal[0] = g; scal[1] = A; scal[2] = Bb; scal[3] = g - A + Bb;
  }
  __syncthreads();
  double gamma = rr[32], loss = rr[35];
  double ed = rr[33], dAd = rr[34];
  __syncthreads();

  int pos = 0, rc = 0;
  while (pos < NN) {
    int b2 = rc & 1; ++rc;
    // phase A: flag live positions in window [pos, pos+1024)
    {
      int P = pos + t;
      int f = 0;
      if (P < NN) {
        int ix = ordl[P];
        f = !((decidedL[ix >> 5] >> (ix & 31)) & 1u);
      }
      u64 bal = __ballot(f);
      if (lane == 0) wbalL[w] = bal;
    }
    __syncthreads();
    // phase B: wave w -> w-th live position (mapping replicated across 16-lane subgroups)
    int myc = __popcll(wbalL[lane & 15]);
    int pre = myc;
    #pragma unroll
    for (int d = 1; d < 16; d <<= 1) {
      int v = __shfl_up(pre, d, 16);
      if ((lane & 15) >= d) pre += v;
    }
    int total = __shfl(pre, 15, 16);
    int exc = pre - myc;
    int myP = -1;
    if (w < total) {
      bool hit = (exc <= w) && (w < pre);
      u64 bal2 = __ballot(hit) & 0xffffull;
      int word = (int)__builtin_ctzll(bal2);
      int excw = __shfl(exc, word, 16);
      int r = w - excw;
      u64 bits = wbalL[word];
      for (int k2 = 0; k2 < r; ++k2) bits &= bits - 1;
      myP = pos + (word << 6) + (int)__builtin_ctzll(bits);
    }
    if (myP >= 0) {
      if (lane == 0) svP[b2][w] = myP;
      int idx = ordl[myP];
      uint2 rt = rtP[idx];
      int r0 = rt.x & 0xffff, r1 = rt.y & 0xffff;
      int t0 = rt.x >> 16, t1 = rt.y >> 16;
      float2 dqi = dq[idx];   // broadcast
      float2 eei = ee[idx];   // broadcast
      float s2 = 0.f, st = 0.f;
      for (int e = r0 + lane; e < r1; e += 64) {
        float2 v = dq[colL[e]];
        s2 -= v.y * v.x;
      }
      if (t1 <= TRI_LDS) {
        for (int e = t0 + lane; e < t1; e += 64) {
          ushort2 ab = triL[e];
          st += dq[ab.x].x * dq[ab.y].x;
        }
      } else {  // rare overflow: true offsets + pairs from global
        int g0 = tp[idx], g1 = tp[idx + 1];
        if (g0 > TRI_CAP) g0 = TRI_CAP;
        if (g1 > TRI_CAP) g1 = TRI_CAP;
        for (int e = g0 + lane; e < g1; e += 64) {
          int2 ab = tri[e];
          st += dq[ab.x].x * dq[ab.y].x;
        }
      }
      red2(s2, st);
      float d0 = 1.f - dqi.x;
      float S1 = -eei.y + eei.x * d0;
      float S2 = s2 + dqi.y * d0;
      float sn = -dqi.y;
      double cross = 2.0 * (double)d0 * (double)sn + (double)st;
      double li = gamma - (ed + (double)S1) + (dAd + 2.0 * (double)S2 + cross);
      if (li <= loss && lane == 0) {
        svA[b2][w] = make_float4(S1, S2, d0, st);
        svQ[b2][w] = dqi.y;
        atomicOr(&maskL[b2], 1u << w);
      }
    }
    __syncthreads();
    unsigned mask = maskL[b2];
    if (mask == 0u) {
      pos = (total >= 16) ? (svP[b2][15] + 1) : (pos + 1024);
      continue;
    }
    int k = __builtin_ctz(mask);
    int Pk = svP[b2][k];
    int idx = ordl[Pk];
    float4 A = svA[b2][k];    // {S1, S2, d0, st}
    float qi = svQ[b2][k];    // old q[idx] saved at eval (q unchanged since)
    uint2 rt = rtP[idx];
    int r0 = rt.x & 0xffff, r1 = rt.y & 0xffff;
    {
      double cross = 2.0 * (double)A.z * (double)(-qi) + (double)A.w;
      ed += (double)A.x;
      dAd += 2.0 * (double)A.y + cross;
    }
    // phase 1: q/E scatter with OLD d (all eval reads completed at round barrier)
    for (int e = r0 + w; e < r1; e += 16) {
      int a = colL[e];
      float da = -dq[a].x;
      if (da != 0.f) {
        float ea = ee[a].x;
        uint2 art = rtP[a];
        int b0 = art.x & 0xffff, b1 = art.y & 0xffff;
        for (int eb = b0 + lane; eb < b1; eb += 64) {
          int bb = colL[eb];
          atomicAdd(&dq[bb].y, da);
          atomicAdd(&ee[bb].y, ea * da);
        }
      }
    }
    {
      float ei = ee[idx].x;
      for (int e = r0 + t; e < r1; e += 1024) {
        int bb = colL[e];
        atomicAdd(&dq[bb].y, A.z);
        atomicAdd(&ee[bb].y, ei * A.z);
      }
    }
    __syncthreads();
    // phase 2: d updates + decided/sel bits + mask reset
    if (t == 0) {
      dq[idx].x = 1.f;
      atomicOr(&decidedL[idx >> 5], 1u << (idx & 31));
      atomicOr(&selL[idx >> 5], 1u << (idx & 31));
      maskL[b2] = 0u;
    }
    for (int e = r0 + t; e < r1; e += 1024) {
      int j = colL[e];
      dq[j].x = 0.f;
      atomicOr(&decidedL[j >> 5], 1u << (j & 31));
    }
    __syncthreads();
    pos = Pk + 1;
  }
  for (int i = t; i < NN; i += 1024)
    selb_g[i] = (u8)((selL[i >> 5] >> (i & 31)) & 1u);
}

// ---------------- boolean A^2 / A^3 ----------------
__global__ void k_reach(const u64* __restrict__ src, const int* __restrict__ rp,
                        const int* __restrict__ col, u64* __restrict__ dst) {
  int node = blockIdx.x * 2 + (threadIdx.x >> 5);
  int w = threadIdx.x & 31;
  u64 acc = 0;
  for (int e = rp[node]; e < rp[node + 1]; ++e) acc |= src[((size_t)col[e] << 5) + w];
  dst[((size_t)node << 5) + w] = acc;
}

// ---------------- outputs (fused) ----------------
__global__ void k_out(const u64* __restrict__ row2, const u64* __restrict__ row3,
                      const u8* __restrict__ selb, const float* __restrict__ x,
                      const int* __restrict__ batch, const double* __restrict__ scal,
                      float* __restrict__ o_x, float* __restrict__ o_adj,
                      float* __restrict__ o_sel, float* __restrict__ o_bat,
                      float* __restrict__ o_loss) {
  int idx = blockIdx.x * blockDim.x + threadIdx.x; // NN*NN
  {
    int i = idx >> 11, j = idx & 2047;
    int wo = (i << 5) + (j >> 6);
    u64 b = (row2[wo] | row3[wo]) >> (j & 63);
    o_adj[idx] = ((b & 1ull) && i != j && selb[i] && selb[j]) ? 1.f : 0.f;
  }
  if (idx < NN * DIMF) {
    int i = idx >> 8;
    o_x[idx] = selb[i] ? x[idx] : 0.f;
  }
  if (idx < NN) {
    o_sel[idx] = selb[idx] ? 1.f : 0.f;
    o_bat[idx] = selb[idx] ? (float)batch[idx] : -1.f;
  }
  if (idx == 0) o_loss[0] = (float)scal[3];
}

extern "C" void kernel_launch(void* const* d_in, const int* in_sizes, int n_in,
                              void* d_out, int out_size, void* d_ws, size_t ws_size,
                              hipStream_t stream) {
  const float* x    = (const float*)d_in[0];
  const int*   ei   = (const int*)d_in[1];
  const int*   batch= (const int*)d_in[2];
  const float* w11  = (const float*)d_in[3];
  const float* b11  = (const float*)d_in[4];
  const float* g1   = (const float*)d_in[5];
  const float* be1  = (const float*)d_in[6];
  const float* w12  = (const float*)d_in[7];
  const float* b12  = (const float*)d_in[8];
  const float* w21  = (const float*)d_in[9];
  const float* b21  = (const float*)d_in[10];
  const float* g2   = (const float*)d_in[11];
  const float* be2  = (const float*)d_in[12];
  const float* w22  = (const float*)d_in[13];
  const float* b22  = (const float*)d_in[14];
  const float* w31  = (const float*)d_in[15];
  const float* b31  = (const float*)d_in[16];
  const float* g3   = (const float*)d_in[17];
  const float* be3  = (const float*)d_in[18];
  const float* w32  = (const float*)d_in[19];
  const float* b32  = (const float*)d_in[20];

  char* wsb = (char*)d_ws;
  size_t cur = 0;
  auto alloc = [&](size_t bytes) -> void* {
    void* pp = wsb + cur;
    cur += (bytes + 255) & ~(size_t)255;
    return pp;
  };
  u64*    rowbits = (u64*)alloc((size_t)NN * W32 * 8);
  u64*    row2    = (u64*)alloc((size_t)NN * W32 * 8);
  u64*    row3    = (u64*)alloc((size_t)NN * W32 * 8);
  double* seggam  = (double*)alloc(NG * 8);
  double* scal    = (double*)alloc(4 * 8);
  int*    rowptr  = (int*)alloc((NN + 1) * 4);
  int*    colx    = (int*)alloc(65536 * 4);
  int*    tricnt  = (int*)alloc(NN * 4);
  int*    triptr  = (int*)alloc((NN + 1) * 4);
  int2*   tri     = (int2*)alloc((size_t)TRI_CAP * 8);
  int*    segst   = (int*)alloc((NG + 1) * 4);
  int*    order   = (int*)alloc(NN * 4);
  float*  ent     = (float*)alloc(NN * 4);
  float*  V       = (float*)alloc(NN * 4);
  float*  p       = (float*)alloc(NN * 4);
  float*  agg1    = (float*)alloc(NN * 4);
  float*  scale   = (float*)alloc(HIDN * 4);
  float*  shift   = (float*)alloc(HIDN * 4);
  float*  tA      = (float*)alloc((size_t)NN * HIDN * 4);
  float*  tB      = (float*)alloc((size_t)NN * HIDN * 4);
  float*  tC      = (float*)alloc((size_t)NN * HIDN * 4);
  u8*     selb    = (u8*)alloc(NN);

  float* out    = (float*)d_out;
  float* o_x    = out;                       // 524288
  float* o_adj  = out + 524288;              // 4194304
  float* o_sel  = out + 4718592;             // 2048
  float* o_bat  = out + 4720640;             // 2048
  float* o_loss = out + 4722688;             // 1

  k_init<<<64, 256, 0, stream>>>(rowbits, segst);
  k_edges<<<128, 256, 0, stream>>>(ei, rowbits);
  k_degscan<<<1, 256, 0, stream>>>(rowbits, batch, segst, rowptr);
  k_extract<<<8, 256, 0, stream>>>(rowbits, rowptr, colx, tricnt);
  k_scan2048<<<1, 256, 0, stream>>>(tricnt, triptr);
  k_trifill<<<8, 256, 0, stream>>>(rowbits, rowptr, colx, triptr, tri);
  k_V<<<NN, 256, 0, stream>>>(x, rowptr, colx, V);
  k_soft<<<NG, 256, 0, stream>>>(V, segst, ent, seggam);

  // layer 1 (lin1 fused into bn1 + mm1)
  k_agg1<<<8, 256, 0, stream>>>(ent, rowptr, colx, agg1);
  k_bn<1><<<HIDN, 256, 0, stream>>>(agg1, w11, b11, g1, be1, scale, shift);
  k_mm<2, 0><<<NN / 8, HIDN, 0, stream>>>(agg1, w12, b12, scale, shift, w11, b11, tB);
  // layer 2
  k_agg128<<<NN, HIDN, 0, stream>>>(tB, rowptr, colx, tC);
  k_mm<0, 1><<<NN / 8, HIDN, 0, stream>>>(tC, w21, b21, scale, shift, (const float*)0, (const float*)0, tA);
  k_bn<0><<<HIDN, 256, 0, stream>>>(tA, (const float*)0, (const float*)0, g2, be2, scale, shift);
  k_mm<1, 0><<<NN / 8, HIDN, 0, stream>>>(tA, w22, b22, scale, shift, (const float*)0, (const float*)0, tB);
  // layer 3
  k_agg128<<<NN, HIDN, 0, stream>>>(tB, rowptr, colx, tC);
  k_mm<0, 1><<<NN / 8, HIDN, 0, stream>>>(tC, w31, b31, scale, shift, (const float*)0, (const float*)0, tA);
  k_bn<0><<<HIDN, 256, 0, stream>>>(tA, (const float*)0, (const float*)0, g3, be3, scale, shift);
  k_lin3<<<NN, HIDN, 0, stream>>>(tA, scale, shift, w32, b32, p);

  k_sort<<<1, 1024, 0, stream>>>(p, order);
  k_greedy<<<1, 1024, 0, stream>>>(rowptr, colx, triptr, tri, order, p, ent, seggam, scal, selb);

  k_reach<<<NN / 2, 64, 0, stream>>>(rowbits, rowptr, colx, row2);
  k_reach<<<NN / 2, 64, 0, stream>>>(row2, rowptr, colx, row3);
  k_out<<<NN * NN / 256, 256, 0, stream>>>(row2, row3, selb, x, batch, scal,
                                           o_x, o_adj, o_sel, o_bat, o_loss);

  (void)in_sizes; (void)n_in; (void)out_size; (void)ws_size;
}